// Round 11
// baseline (152.478 us; speedup 1.0000x reference)
//
#include <hip/hip_runtime.h>
#include <math.h>

typedef __bf16 bf16_t;
typedef bf16_t bf16x4 __attribute__((ext_vector_type(4)));
typedef bf16_t bf16x8 __attribute__((ext_vector_type(8)));
typedef float  f32x4  __attribute__((ext_vector_type(4)));

__device__ __forceinline__ float softplus_f(float x) {
    return (x > 20.f) ? x : log1pf(expf(x));
}

__device__ __forceinline__ float fast_rcp(float x) {
#if __has_builtin(__builtin_amdgcn_rcpf)
    return __builtin_amdgcn_rcpf(x);
#else
    return 1.0f / x;
#endif
}

// ---------------- gemm: 64x64 tile, intra-block split-K, fused W-transpose+convert ----------------
// A: fp32 [m][k] (afp32=1) or bf16 [m][k] (afp32=0). W: fp32 [k][n] (original layout).
struct GemmArgs {
    const void*  A[6];
    const float* W[6];
    const float* bias[6];
    float*       dst[6];
    int          splus[6];
    int          afp32[6];
};

__global__ __launch_bounds__(256, 2) void gemm_splitk(GemmArgs args) {
    const int z = blockIdx.z;
    const float* __restrict__ Wf   = args.W[z];
    const float* __restrict__ bias = args.bias[z];
    float*       __restrict__ dst  = args.dst[z];
    const int sp = args.splus[z];
    const int af = args.afp32[z];

    const int n_base = blockIdx.x * 64;
    const int m_base = blockIdx.y * 64;

    __shared__ __align__(16) unsigned char smem_raw[73728];
    bf16_t* stage = (bf16_t*)smem_raw;
    float*  Cr    = (float*)smem_raw;

    const int t = threadIdx.x;
    const int lane = t & 63;
    const int w = t >> 6;
    bf16_t* As = stage + w * 9216;
    bf16_t* Bs = As + 4608;

    const int r8 = lane >> 3, kb = lane & 7;     // A staging map
    const int nq = lane & 15, kg = lane >> 4;    // B staging map (transpose)
    const int fr = lane & 15, fq = lane >> 4, fk = fq * 8;

    f32x4 acc[4][4] = {};

#pragma unroll
    for (int s = 0; s < 4; ++s) {
        const int k0 = w * 256 + s * 64;
        // ---- A staging ----
        if (af) {
            const float* Af = (const float*)args.A[z];
#pragma unroll
            for (int i = 0; i < 8; ++i) {
                const int row = i * 8 + r8;
                const float* src = Af + (size_t)(m_base + row) * 1024 + k0 + kb * 8;
                f32x4 v0 = *(const f32x4*)src;
                f32x4 v1 = *(const f32x4*)(src + 4);
                bf16x8 o;
                o[0] = (bf16_t)v0[0]; o[1] = (bf16_t)v0[1]; o[2] = (bf16_t)v0[2]; o[3] = (bf16_t)v0[3];
                o[4] = (bf16_t)v1[0]; o[5] = (bf16_t)v1[1]; o[6] = (bf16_t)v1[2]; o[7] = (bf16_t)v1[3];
                *(bf16x8*)&As[row * 72 + kb * 8] = o;
            }
        } else {
            const bf16_t* Ab = (const bf16_t*)args.A[z];
#pragma unroll
            for (int i = 0; i < 8; ++i) {
                const int row = i * 8 + r8;
                bf16x8 av = *(const bf16x8*)&Ab[(size_t)(m_base + row) * 1024 + k0 + kb * 8];
                *(bf16x8*)&As[row * 72 + kb * 8] = av;
            }
        }
        // ---- B staging: transpose W[k][n] fp32 -> Bs[n][k] bf16 ----
#pragma unroll
        for (int sub = 0; sub < 2; ++sub) {
            f32x4 v[8];
#pragma unroll
            for (int j = 0; j < 8; ++j)
                v[j] = *(const f32x4*)&Wf[(size_t)(k0 + kg * 16 + sub * 8 + j) * 1024 + n_base + nq * 4];
#pragma unroll
            for (int ii = 0; ii < 4; ++ii) {
                const int e = (kg + ii) & 3;   // bank-spread rotation
                bf16x8 o;
#pragma unroll
                for (int j = 0; j < 8; ++j) o[j] = (bf16_t)v[j][e];
                *(bf16x8*)&Bs[(nq * 4 + e) * 72 + kg * 16 + sub * 8] = o;
            }
        }
        // ---- MFMA ----
#pragma unroll
        for (int kh = 0; kh < 2; ++kh) {
            bf16x8 aF[4], bF[4];
#pragma unroll
            for (int i = 0; i < 4; ++i)
                aF[i] = *(const bf16x8*)&As[(i * 16 + fr) * 72 + kh * 32 + fk];
#pragma unroll
            for (int j = 0; j < 4; ++j)
                bF[j] = *(const bf16x8*)&Bs[(j * 16 + fr) * 72 + kh * 32 + fk];
#pragma unroll
            for (int i = 0; i < 4; ++i)
#pragma unroll
                for (int j = 0; j < 4; ++j)
                    acc[i][j] = __builtin_amdgcn_mfma_f32_16x16x32_bf16(aF[i], bF[j], acc[i][j], 0, 0, 0);
        }
    }

    __syncthreads();
    {
        float* Crw = Cr + w * 4352;
        const int orow = fq * 4;
#pragma unroll
        for (int i = 0; i < 4; ++i)
#pragma unroll
            for (int j = 0; j < 4; ++j)
#pragma unroll
                for (int rr = 0; rr < 4; ++rr)
                    Crw[(i * 16 + orow + rr) * 68 + j * 16 + fr] = acc[i][j][rr];
    }
    __syncthreads();

    const int cc = (t & 15) * 4;
    f32x4 bv4 = *(const f32x4*)&bias[n_base + cc];
#pragma unroll
    for (int i = 0; i < 4; ++i) {
        const int row = (t >> 4) + i * 16;
        f32x4 s0 = *(const f32x4*)&Cr[0 * 4352 + row * 68 + cc];
        f32x4 s1 = *(const f32x4*)&Cr[1 * 4352 + row * 68 + cc];
        f32x4 s2 = *(const f32x4*)&Cr[2 * 4352 + row * 68 + cc];
        f32x4 s3 = *(const f32x4*)&Cr[3 * 4352 + row * 68 + cc];
        f32x4 v = (s0 + s1) + (s2 + s3) + bv4;
        if (sp) {
            v[0] = softplus_f(v[0]); v[1] = softplus_f(v[1]);
            v[2] = softplus_f(v[2]); v[3] = softplus_f(v[3]);
        }
        *(f32x4*)&dst[(size_t)(m_base + row) * 1024 + n_base + cc] = v;
    }
}

// ---------------- feat: Gbf[h][katt=256][d=128] bf16 (MFMA B-layout) + cvec[h][katt] ----------------
__global__ __launch_bounds__(256) void feat_kernel(const float* __restrict__ Km,
                                                   const float* __restrict__ Kv,
                                                   bf16_t* __restrict__ Gbf,
                                                   float* __restrict__ cvec) {
    const int h = blockIdx.x, kb = blockIdx.y;
    const int t = threadIdx.x;
    const int kx = t & 63;
    const int dg = t >> 6;
    const int katt = kb * 64 + kx;
    const float* kvp = Kv + (size_t)katt * 1024 + h * 64 + dg * 16;
    const float* kmp = Km + (size_t)katt * 1024 + h * 64 + dg * 16;
    bf16_t* grow = Gbf + ((size_t)(h * 256 + katt)) * 128;
    float cp = 0.f;
#pragma unroll
    for (int c = 0; c < 4; ++c) {
        f32x4 kv = *(const f32x4*)(kvp + c * 4);
        f32x4 km = *(const f32x4*)(kmp + c * 4);
        bf16x4 o1, o2;
#pragma unroll
        for (int e = 0; e < 4; ++e) {
            const float r = 0.5f * fast_rcp(kv[e]);
            o1[e] = (bf16_t)r;
            o2[e] = (bf16_t)(-2.f * km[e] * r);
            cp += km[e] * km[e] * r + 0.5f * __logf(kv[e]);
        }
        *(bf16x4*)&grow[dg * 16 + c * 4]      = o1;
        *(bf16x4*)&grow[64 + dg * 16 + c * 4] = o2;
    }
    __shared__ float red[4][64];
    red[dg][kx] = cp;
    __syncthreads();
    if (dg == 0)
        cvec[h * 256 + katt] = red[0][kx] + red[1][kx] + red[2][kx] + red[3][kx];
}

// ---------------- attn_v6: MFMA scores + MFMA PV (R8-verified) ----------------
#define OFF_VM   0
#define OFF_VV   36864
#define OFF_FS   73728
#define OFF_SC   82176
#define OFF_PHI  98816
#define OFF_PLO  107264
#define OFF_P2H  115712
#define OFF_P2L  124160
#define ATTN_SMEM 132608

__global__ __launch_bounds__(256) void attn_v6(const float* __restrict__ Qm,
                                               const float* __restrict__ Qv,
                                               const bf16_t* __restrict__ Gbf,
                                               const float* __restrict__ cvec,
                                               const float* __restrict__ Vm,
                                               const float* __restrict__ Vv,
                                               bf16_t* __restrict__ Omu,
                                               bf16_t* __restrict__ Ovar) {
    __shared__ __align__(16) unsigned char smem[ATTN_SMEM];
    bf16_t* Vsm = (bf16_t*)(smem + OFF_VM);
    bf16_t* Vsv = (bf16_t*)(smem + OFF_VV);
    float*  Fs  = (float*)(smem + OFF_FS);
    float*  Sc  = (float*)(smem + OFF_SC);
    bf16_t* Phi = (bf16_t*)(smem + OFF_PHI);
    bf16_t* Plo = (bf16_t*)(smem + OFF_PLO);
    bf16_t* P2h = (bf16_t*)(smem + OFF_P2H);
    bf16_t* P2l = (bf16_t*)(smem + OFF_P2L);

    const int qt = blockIdx.x, h = blockIdx.y;
    const int t = threadIdx.x, w = t >> 6, lane = t & 63;
    const int fr = lane & 15, fq = lane >> 4;
    const int n0 = w * 64;

    const bf16_t* gB = Gbf + ((size_t)(h * 256 + n0 + fr)) * 128 + fq * 8;

    bf16x8 bcur[4];
#pragma unroll
    for (int ks = 0; ks < 4; ++ks) bcur[ks] = *(const bf16x8*)(gB + ks * 32);

    {
        const int r = t >> 4, c = t & 15;
        f32x4 qm = *(const f32x4*)(Qm + (size_t)(qt * 16 + r) * 1024 + h * 64 + c * 4);
        f32x4 qv = *(const f32x4*)(Qv + (size_t)(qt * 16 + r) * 1024 + h * 64 + c * 4);
        *(f32x4*)&Fs[r * 132 + c * 4]      = qm * qm + qv;
        *(f32x4*)&Fs[r * 132 + 64 + c * 4] = qm;
    }
    __syncthreads();

    bf16x8 ahi[4], alo[4];
#pragma unroll
    for (int ks = 0; ks < 4; ++ks) {
        f32x4 f0 = *(const f32x4*)&Fs[fr * 132 + ks * 32 + fq * 8];
        f32x4 f1 = *(const f32x4*)&Fs[fr * 132 + ks * 32 + fq * 8 + 4];
#pragma unroll
        for (int e = 0; e < 4; ++e) {
            bf16_t hb = (bf16_t)f0[e];
            ahi[ks][e] = hb; alo[ks][e] = (bf16_t)(f0[e] - (float)hb);
            bf16_t hb2 = (bf16_t)f1[e];
            ahi[ks][e + 4] = hb2; alo[ks][e + 4] = (bf16_t)(f1[e] - (float)hb2);
        }
    }

    const int vk = t >> 2, vpart = t & 3;
#pragma unroll
    for (int nt = 0; nt < 4; ++nt) {
        const int ua = 2 * nt, ub = 2 * nt + 1;
        const float* vsa = ((ua >> 2) ? Vv : Vm) + (size_t)(vk + (ua & 3) * 64) * 1024 + h * 64 + vpart * 16;
        const float* vsb = ((ub >> 2) ? Vv : Vm) + (size_t)(vk + (ub & 3) * 64) * 1024 + h * 64 + vpart * 16;
        f32x4 va0 = *(const f32x4*)(vsa),     va1 = *(const f32x4*)(vsa + 4);
        f32x4 va2 = *(const f32x4*)(vsa + 8), va3 = *(const f32x4*)(vsa + 12);
        f32x4 vb0 = *(const f32x4*)(vsb),     vb1 = *(const f32x4*)(vsb + 4);
        f32x4 vb2 = *(const f32x4*)(vsb + 8), vb3 = *(const f32x4*)(vsb + 12);

        bf16x8 bnxt[4];
        if (nt < 3) {
#pragma unroll
            for (int ks = 0; ks < 4; ++ks)
                bnxt[ks] = *(const bf16x8*)(gB + (size_t)(nt + 1) * 2048 + ks * 32);
        }

        f32x4 acc = {0.f, 0.f, 0.f, 0.f};
#pragma unroll
        for (int ks = 0; ks < 4; ++ks) {
            acc = __builtin_amdgcn_mfma_f32_16x16x32_bf16(ahi[ks], bcur[ks], acc, 0, 0, 0);
            acc = __builtin_amdgcn_mfma_f32_16x16x32_bf16(alo[ks], bcur[ks], acc, 0, 0, 0);
        }

        {
            bf16_t* da = ((ua >> 2) ? Vsv : Vsm) + (vk + (ua & 3) * 64) * 72 + vpart * 16;
            bf16_t* db = ((ub >> 2) ? Vsv : Vsm) + (vk + (ub & 3) * 64) * 72 + vpart * 16;
            bf16x8 o0, o1;
            o0[0]=(bf16_t)va0[0]; o0[1]=(bf16_t)va0[1]; o0[2]=(bf16_t)va0[2]; o0[3]=(bf16_t)va0[3];
            o0[4]=(bf16_t)va1[0]; o0[5]=(bf16_t)va1[1]; o0[6]=(bf16_t)va1[2]; o0[7]=(bf16_t)va1[3];
            o1[0]=(bf16_t)va2[0]; o1[1]=(bf16_t)va2[1]; o1[2]=(bf16_t)va2[2]; o1[3]=(bf16_t)va2[3];
            o1[4]=(bf16_t)va3[0]; o1[5]=(bf16_t)va3[1]; o1[6]=(bf16_t)va3[2]; o1[7]=(bf16_t)va3[3];
            *(bf16x8*)(da)     = o0;
            *(bf16x8*)(da + 8) = o1;
            o0[0]=(bf16_t)vb0[0]; o0[1]=(bf16_t)vb0[1]; o0[2]=(bf16_t)vb0[2]; o0[3]=(bf16_t)vb0[3];
            o0[4]=(bf16_t)vb1[0]; o0[5]=(bf16_t)vb1[1]; o0[6]=(bf16_t)vb1[2]; o0[7]=(bf16_t)vb1[3];
            o1[0]=(bf16_t)vb2[0]; o1[1]=(bf16_t)vb2[1]; o1[2]=(bf16_t)vb2[2]; o1[3]=(bf16_t)vb2[3];
            o1[4]=(bf16_t)vb3[0]; o1[5]=(bf16_t)vb3[1]; o1[6]=(bf16_t)vb3[2]; o1[7]=(bf16_t)vb3[3];
            *(bf16x8*)(db)     = o0;
            *(bf16x8*)(db + 8) = o1;
        }

        const float cv = cvec[h * 256 + n0 + nt * 16 + fr];
        f32x4 lg = (acc + cv) * (-0.125f);
#pragma unroll
        for (int reg = 0; reg < 4; ++reg)
            Sc[(fq * 4 + reg) * 260 + n0 + nt * 16 + fr] = lg[reg];

#pragma unroll
        for (int ks = 0; ks < 4; ++ks) bcur[ks] = bnxt[ks];
    }
    __syncthreads();

    const int fw = w * 4;
    f32x4 sr[4];
#pragma unroll
    for (int r = 0; r < 4; ++r)
        sr[r] = *(const f32x4*)&Sc[(fw + r) * 260 + lane * 4];
#pragma unroll
    for (int r = 0; r < 4; ++r) {
        f32x4 s = sr[r];
        float mloc = fmaxf(fmaxf(s[0], s[1]), fmaxf(s[2], s[3]));
#pragma unroll
        for (int off = 32; off > 0; off >>= 1)
            mloc = fmaxf(mloc, __shfl_xor(mloc, off, 64));
        s[0] = __expf(s[0] - mloc); s[1] = __expf(s[1] - mloc);
        s[2] = __expf(s[2] - mloc); s[3] = __expf(s[3] - mloc);
        float sl = (s[0] + s[1]) + (s[2] + s[3]);
#pragma unroll
        for (int off = 32; off > 0; off >>= 1)
            sl += __shfl_xor(sl, off, 64);
        sr[r] = s * fast_rcp(sl);
    }

#pragma unroll
    for (int r = 0; r < 4; ++r) {
        bf16x4 phi, plo, p2hi, p2lo;
#pragma unroll
        for (int e = 0; e < 4; ++e) {
            const float p = sr[r][e];
            const bf16_t hb = (bf16_t)p;
            phi[e] = hb; plo[e] = (bf16_t)(p - (float)hb);
            const float p2 = p * p;
            const bf16_t h2 = (bf16_t)p2;
            p2hi[e] = h2; p2lo[e] = (bf16_t)(p2 - (float)h2);
        }
        const int row = fw + r;
        *(bf16x4*)&Phi[row * 264 + lane * 4] = phi;
        *(bf16x4*)&Plo[row * 264 + lane * 4] = plo;
        *(bf16x4*)&P2h[row * 264 + lane * 4] = p2hi;
        *(bf16x4*)&P2l[row * 264 + lane * 4] = p2lo;
    }
    __syncthreads();

    f32x4 accm = {0.f,0.f,0.f,0.f}, accv = {0.f,0.f,0.f,0.f};
#pragma unroll
    for (int k0 = 0; k0 < 256; k0 += 32) {
        const int ka = k0 + fq * 8;
        bf16x8 ahi2 = *(const bf16x8*)&Phi[fr * 264 + ka];
        bf16x8 alo2 = *(const bf16x8*)&Plo[fr * 264 + ka];
        bf16x8 a2h  = *(const bf16x8*)&P2h[fr * 264 + ka];
        bf16x8 a2l  = *(const bf16x8*)&P2l[fr * 264 + ka];
        bf16x8 bm, bv;
#pragma unroll
        for (int j = 0; j < 8; ++j) {
            const int kk = ka + j;
            bm[j] = Vsm[kk * 72 + w * 16 + fr];
            bv[j] = Vsv[kk * 72 + w * 16 + fr];
        }
        accm = __builtin_amdgcn_mfma_f32_16x16x32_bf16(ahi2, bm, accm, 0, 0, 0);
        accm = __builtin_amdgcn_mfma_f32_16x16x32_bf16(alo2, bm, accm, 0, 0, 0);
        accv = __builtin_amdgcn_mfma_f32_16x16x32_bf16(a2h,  bv, accv, 0, 0, 0);
        accv = __builtin_amdgcn_mfma_f32_16x16x32_bf16(a2l,  bv, accv, 0, 0, 0);
    }

#pragma unroll
    for (int reg = 0; reg < 4; ++reg) {
        const int qg = qt * 16 + fq * 4 + reg;
        const size_t ob = (size_t)qg * 1024 + h * 64 + w * 16 + fr;
        Omu[ob]  = (bf16_t)accm[reg];
        Ovar[ob] = (bf16_t)accv[reg];
    }
}

// ---------------- launch ----------------
extern "C" void kernel_launch(void* const* d_in, const int* in_sizes, int n_in,
                              void* d_out, int out_size, void* d_ws, size_t ws_size,
                              hipStream_t stream) {
    const float* mu  = (const float*)d_in[0];
    const float* var = (const float*)d_in[1];

    uint8_t* ws = (uint8_t*)d_ws;
    float*  Proj    = (float*)(ws + (17u << 20));                 // 6 x 1 MB
    bf16_t* Obf_mu  = (bf16_t*)(ws + (23u << 20));                // 512 KB
    bf16_t* Obf_var = (bf16_t*)(ws + (23u << 20) + (512u << 10)); // 512 KB
    bf16_t* Gbf     = (bf16_t*)(ws + (24u << 20));                // 1 MB
    float*  cvec    = (float*)(ws + (25u << 20));                 // 16 KB

    // K1: six projection GEMMs (Qm, Qv, Km, Kv, Vm, Vv) — fp32 A, fused W transpose
    GemmArgs g1;
    for (int z = 0; z < 6; ++z) {
        g1.A[z]     = (z & 1) ? (const void*)var : (const void*)mu;
        g1.W[z]     = (const float*)d_in[2 + 2 * z];
        g1.bias[z]  = (const float*)d_in[3 + 2 * z];
        g1.dst[z]   = Proj + (size_t)z * 262144;
        g1.splus[z] = (z & 1);
        g1.afp32[z] = 1;
    }
    gemm_splitk<<<dim3(16, 4, 6), 256, 0, stream>>>(g1);

    feat_kernel<<<dim3(16, 4), 256, 0, stream>>>(Proj + 2 * 262144, Proj + 3 * 262144, Gbf, cvec);

    attn_v6<<<dim3(16, 16), 256, 0, stream>>>(Proj,
                                              Proj + 262144,
                                              Gbf, cvec,
                                              Proj + 4 * 262144,
                                              Proj + 5 * 262144,
                                              Obf_mu, Obf_var);

    // K3: output projections -> d_out — bf16 A (attn output), fused W transpose
    GemmArgs g3;
    for (int z = 0; z < 6; ++z) {
        g3.A[z]     = (const void*)Obf_mu;
        g3.W[z]     = (const float*)d_in[14];
        g3.bias[z]  = (const float*)d_in[15];
        g3.dst[z]   = (float*)d_out;
        g3.splus[z] = 0;
        g3.afp32[z] = 0;
    }
    g3.A[1]    = (const void*)Obf_var;
    g3.W[1]    = (const float*)d_in[16];
    g3.bias[1] = (const float*)d_in[17];
    g3.dst[1]  = (float*)d_out + 262144;
    g3.splus[1] = 1;
    gemm_splitk<<<dim3(16, 4, 2), 256, 0, stream>>>(g3);
}

// Round 13
// 148.913 us; speedup vs baseline: 1.0239x; 1.0239x over previous
//
#include <hip/hip_runtime.h>
#include <math.h>

typedef __bf16 bf16_t;
typedef bf16_t bf16x4 __attribute__((ext_vector_type(4)));
typedef bf16_t bf16x8 __attribute__((ext_vector_type(8)));
typedef float  f32x4  __attribute__((ext_vector_type(4)));

__device__ __forceinline__ float softplus_f(float x) {
    return (x > 20.f) ? x : log1pf(expf(x));
}

__device__ __forceinline__ float fast_rcp(float x) {
#if __has_builtin(__builtin_amdgcn_rcpf)
    return __builtin_amdgcn_rcpf(x);
#else
    return 1.0f / x;
#endif
}

// ---------------- prep: z<8 transpose+convert weights, z==8 convert activations ----------------
struct PrepArgs { const float* src[8]; const float* mu; const float* var; };

__global__ __launch_bounds__(256) void prep_kernel(PrepArgs pa, bf16_t* __restrict__ wtbase,
                                                   bf16_t* __restrict__ dmu, bf16_t* __restrict__ dvar) {
    const int t = threadIdx.x;
    if (blockIdx.z == 8) {
        const int gid = (blockIdx.y * 16 + blockIdx.x) * 256 + t;   // 0..65535
        const float* s; bf16_t* d; int off;
        if (gid < 32768) { s = pa.mu;  d = dmu;  off = gid * 8; }
        else             { s = pa.var; d = dvar; off = (gid - 32768) * 8; }
        float4 v0 = *(const float4*)(s + off);
        float4 v1 = *(const float4*)(s + off + 4);
        bf16x8 o;
        o[0] = (bf16_t)v0.x; o[1] = (bf16_t)v0.y; o[2] = (bf16_t)v0.z; o[3] = (bf16_t)v0.w;
        o[4] = (bf16_t)v1.x; o[5] = (bf16_t)v1.y; o[6] = (bf16_t)v1.z; o[7] = (bf16_t)v1.w;
        *(bf16x8*)(d + off) = o;
        return;
    }
    const int kt = blockIdx.x, nt = blockIdx.y, wm = blockIdx.z;
    const float* __restrict__ W = pa.src[wm];
    bf16_t* __restrict__ Wt = wtbase + (size_t)wm * 1048576;
    __shared__ bf16_t Ts[64][72];
    const int r0 = t >> 4, c4 = (t & 15) * 4;
#pragma unroll
    for (int rep = 0; rep < 4; ++rep) {
        const int r = r0 + rep * 16;
        const float4 v = *(const float4*)&W[(size_t)(kt * 64 + r) * 1024 + nt * 64 + c4];
        Ts[c4 + 0][r] = (bf16_t)v.x;
        Ts[c4 + 1][r] = (bf16_t)v.y;
        Ts[c4 + 2][r] = (bf16_t)v.z;
        Ts[c4 + 3][r] = (bf16_t)v.w;
    }
    __syncthreads();
#pragma unroll
    for (int rep = 0; rep < 2; ++rep) {
        const int chunk = t + rep * 256;
        const int n = chunk >> 3, kc = (chunk & 7) * 8;
        bf16x8 v = *(const bf16x8*)&Ts[n][kc];
        *(bf16x8*)&Wt[(size_t)(nt * 64 + n) * 1024 + kt * 64 + kc] = v;
    }
}

// ---------------- gemm: 64x64 tile, split-K per wave, register prefetch of next k-slice ----------------
struct GemmArgs {
    const bf16_t* A[6];
    const bf16_t* Wt[6];
    const float*  bias[6];
    float*        dst[6];
    int           splus[6];
};

__global__ __launch_bounds__(256, 2) void gemm_splitk(GemmArgs args) {
    const int z = blockIdx.z;
    const bf16_t* __restrict__ A    = args.A[z];
    const bf16_t* __restrict__ Wt   = args.Wt[z];
    const float*  __restrict__ bias = args.bias[z];
    float*        __restrict__ dst  = args.dst[z];
    const int sp = args.splus[z];

    const int n_base = blockIdx.x * 64;
    const int m_base = blockIdx.y * 64;

    __shared__ __align__(16) unsigned char smem_raw[73728];
    bf16_t* stage = (bf16_t*)smem_raw;
    float*  Cr    = (float*)smem_raw;

    const int t = threadIdx.x;
    const int lane = t & 63;
    const int w = t >> 6;
    bf16_t* As = stage + w * 9216;
    bf16_t* Bs = As + 4608;

    const int r8 = lane >> 3, kb = lane & 7;
    const int fr = lane & 15, fq = lane >> 4, fk = fq * 8;

    const bf16_t* Ab = A  + (size_t)m_base * 1024 + w * 256 + kb * 8;
    const bf16_t* Bb = Wt + (size_t)n_base * 1024 + w * 256 + kb * 8;

    f32x4 acc[4][4] = {};

    // prefetch slice 0 into registers
    bf16x8 pa[8], pb[8];
#pragma unroll
    for (int i = 0; i < 8; ++i) {
        pa[i] = *(const bf16x8*)(Ab + (size_t)(i * 8 + r8) * 1024);
        pb[i] = *(const bf16x8*)(Bb + (size_t)(i * 8 + r8) * 1024);
    }

#pragma unroll
    for (int s = 0; s < 4; ++s) {
#pragma unroll
        for (int i = 0; i < 8; ++i) {
            *(bf16x8*)&As[(i * 8 + r8) * 72 + kb * 8] = pa[i];
            *(bf16x8*)&Bs[(i * 8 + r8) * 72 + kb * 8] = pb[i];
        }
        if (s < 3) {   // issue next slice's loads; in flight during MFMA below
            const int off = (s + 1) * 64;
#pragma unroll
            for (int i = 0; i < 8; ++i) {
                pa[i] = *(const bf16x8*)(Ab + (size_t)(i * 8 + r8) * 1024 + off);
                pb[i] = *(const bf16x8*)(Bb + (size_t)(i * 8 + r8) * 1024 + off);
            }
        }
#pragma unroll
        for (int kh = 0; kh < 2; ++kh) {
            bf16x8 aF[4], bF[4];
#pragma unroll
            for (int i = 0; i < 4; ++i)
                aF[i] = *(const bf16x8*)&As[(i * 16 + fr) * 72 + kh * 32 + fk];
#pragma unroll
            for (int j = 0; j < 4; ++j)
                bF[j] = *(const bf16x8*)&Bs[(j * 16 + fr) * 72 + kh * 32 + fk];
#pragma unroll
            for (int i = 0; i < 4; ++i)
#pragma unroll
                for (int j = 0; j < 4; ++j)
                    acc[i][j] = __builtin_amdgcn_mfma_f32_16x16x32_bf16(aF[i], bF[j], acc[i][j], 0, 0, 0);
        }
    }

    __syncthreads();
    {
        float* Crw = Cr + w * 4352;
        const int orow = fq * 4;
#pragma unroll
        for (int i = 0; i < 4; ++i)
#pragma unroll
            for (int j = 0; j < 4; ++j)
#pragma unroll
                for (int rr = 0; rr < 4; ++rr)
                    Crw[(i * 16 + orow + rr) * 68 + j * 16 + fr] = acc[i][j][rr];
    }
    __syncthreads();

    const int cc = (t & 15) * 4;
    f32x4 bv4 = *(const f32x4*)&bias[n_base + cc];
#pragma unroll
    for (int i = 0; i < 4; ++i) {
        const int row = (t >> 4) + i * 16;
        f32x4 s0 = *(const f32x4*)&Cr[0 * 4352 + row * 68 + cc];
        f32x4 s1 = *(const f32x4*)&Cr[1 * 4352 + row * 68 + cc];
        f32x4 s2 = *(const f32x4*)&Cr[2 * 4352 + row * 68 + cc];
        f32x4 s3 = *(const f32x4*)&Cr[3 * 4352 + row * 68 + cc];
        f32x4 v = (s0 + s1) + (s2 + s3) + bv4;
        if (sp) {
            v[0] = softplus_f(v[0]); v[1] = softplus_f(v[1]);
            v[2] = softplus_f(v[2]); v[3] = softplus_f(v[3]);
        }
        *(f32x4*)&dst[(size_t)(m_base + row) * 1024 + n_base + cc] = v;
    }
}

// ---------------- feat: Gbf[h][katt=256][d=128] bf16 (MFMA B-layout) + cvec[h][katt] ----------------
__global__ __launch_bounds__(256) void feat_kernel(const float* __restrict__ Km,
                                                   const float* __restrict__ Kv,
                                                   bf16_t* __restrict__ Gbf,
                                                   float* __restrict__ cvec) {
    const int h = blockIdx.x, kb = blockIdx.y;
    const int t = threadIdx.x;
    const int kx = t & 63;
    const int dg = t >> 6;
    const int katt = kb * 64 + kx;
    const float* kvp = Kv + (size_t)katt * 1024 + h * 64 + dg * 16;
    const float* kmp = Km + (size_t)katt * 1024 + h * 64 + dg * 16;
    bf16_t* grow = Gbf + ((size_t)(h * 256 + katt)) * 128;
    float cp = 0.f;
#pragma unroll
    for (int c = 0; c < 4; ++c) {
        f32x4 kv = *(const f32x4*)(kvp + c * 4);
        f32x4 km = *(const f32x4*)(kmp + c * 4);
        bf16x4 o1, o2;
#pragma unroll
        for (int e = 0; e < 4; ++e) {
            const float r = 0.5f * fast_rcp(kv[e]);
            o1[e] = (bf16_t)r;
            o2[e] = (bf16_t)(-2.f * km[e] * r);
            cp += km[e] * km[e] * r + 0.5f * __logf(kv[e]);
        }
        *(bf16x4*)&grow[dg * 16 + c * 4]      = o1;
        *(bf16x4*)&grow[64 + dg * 16 + c * 4] = o2;
    }
    __shared__ float red[4][64];
    red[dg][kx] = cp;
    __syncthreads();
    if (dg == 0)
        cvec[h * 256 + katt] = red[0][kx] + red[1][kx] + red[2][kx] + red[3][kx];
}

// ---------------- attn_v7: 512 threads (8 waves), MFMA scores + MFMA PV ----------------
// block (qt, h). wave w: score katt slice [w*32,+32) (2 n-tiles); softmax q rows [2w,2w+2);
// PV: waves 0-3 -> Omu dh tile (w&3), waves 4-7 -> Ovar dh tile (w&3).
// V staging: threads 0-255 stage Vm, 256-511 stage Vv; thread covers rows vk+rep*64,
// cols vpart*16..+16; reps {2nt,2nt+1} interleaved into the 2 score iterations.
#define OFF_VM   0
#define OFF_VV   36864
#define OFF_FS   73728
#define OFF_SC   82176
#define OFF_PHI  98816
#define OFF_PLO  107264
#define OFF_P2H  115712
#define OFF_P2L  124160
#define ATTN_SMEM 132608

__global__ __launch_bounds__(512) void attn_v7(const float* __restrict__ Qm,
                                               const float* __restrict__ Qv,
                                               const bf16_t* __restrict__ Gbf,
                                               const float* __restrict__ cvec,
                                               const float* __restrict__ Vm,
                                               const float* __restrict__ Vv,
                                               bf16_t* __restrict__ Omu,
                                               bf16_t* __restrict__ Ovar) {
    __shared__ __align__(16) unsigned char smem[ATTN_SMEM];
    bf16_t* Vsm = (bf16_t*)(smem + OFF_VM);   // [256][72] bf16
    bf16_t* Vsv = (bf16_t*)(smem + OFF_VV);
    float*  Fs  = (float*)(smem + OFF_FS);    // [16][132] f32
    float*  Sc  = (float*)(smem + OFF_SC);    // [16][260] f32
    bf16_t* Phi = (bf16_t*)(smem + OFF_PHI);  // [16][264] bf16
    bf16_t* Plo = (bf16_t*)(smem + OFF_PLO);
    bf16_t* P2h = (bf16_t*)(smem + OFF_P2H);
    bf16_t* P2l = (bf16_t*)(smem + OFF_P2L);

    const int qt = blockIdx.x, h = blockIdx.y;
    const int t = threadIdx.x, w = t >> 6, lane = t & 63;
    const int fr = lane & 15, fq = lane >> 4;
    const int n0 = w * 32;                    // wave's katt slice base

    const bf16_t* gB = Gbf + ((size_t)(h * 256 + n0 + fr)) * 128 + fq * 8;

    // prefetch B frags for nt=0
    bf16x8 bcur[4];
#pragma unroll
    for (int ks = 0; ks < 4; ++ks) bcur[ks] = *(const bf16x8*)(gB + ks * 32);

    // stage F (threads 0..255 only; v6-identical map)
    if (t < 256) {
        const int r = t >> 4, c = t & 15;
        f32x4 qm = *(const f32x4*)(Qm + (size_t)(qt * 16 + r) * 1024 + h * 64 + c * 4);
        f32x4 qv = *(const f32x4*)(Qv + (size_t)(qt * 16 + r) * 1024 + h * 64 + c * 4);
        *(f32x4*)&Fs[r * 132 + c * 4]      = qm * qm + qv;
        *(f32x4*)&Fs[r * 132 + 64 + c * 4] = qm;
    }
    __syncthreads();

    // A-frags hi/lo from Fs (same for every wave)
    bf16x8 ahi[4], alo[4];
#pragma unroll
    for (int ks = 0; ks < 4; ++ks) {
        f32x4 f0 = *(const f32x4*)&Fs[fr * 132 + ks * 32 + fq * 8];
        f32x4 f1 = *(const f32x4*)&Fs[fr * 132 + ks * 32 + fq * 8 + 4];
#pragma unroll
        for (int e = 0; e < 4; ++e) {
            bf16_t hb = (bf16_t)f0[e];
            ahi[ks][e] = hb; alo[ks][e] = (bf16_t)(f0[e] - (float)hb);
            bf16_t hb2 = (bf16_t)f1[e];
            ahi[ks][e + 4] = hb2; alo[ks][e + 4] = (bf16_t)(f1[e] - (float)hb2);
        }
    }

    // V staging map (block-wide, full coverage): mat from t>>8, rows vk+rep*64, cols vpart*16
    const int tm = t & 255;
    const int vk = tm >> 2, vpart = tm & 3;
    const float* Vsrc = (t >= 256) ? Vv : Vm;
    bf16_t*      Vdst = (t >= 256) ? Vsv : Vsm;

    // score n-tiles: 2 per wave; V reps {2nt, 2nt+1} staged per iteration
#pragma unroll
    for (int nt = 0; nt < 2; ++nt) {
        // issue V loads for reps 2nt, 2nt+1
        const int ra = vk + (2 * nt) * 64;
        const int rb = vk + (2 * nt + 1) * 64;
        const float* vsa = Vsrc + (size_t)ra * 1024 + h * 64 + vpart * 16;
        const float* vsb = Vsrc + (size_t)rb * 1024 + h * 64 + vpart * 16;
        f32x4 va0 = *(const f32x4*)(vsa),     va1 = *(const f32x4*)(vsa + 4);
        f32x4 va2 = *(const f32x4*)(vsa + 8), va3 = *(const f32x4*)(vsa + 12);
        f32x4 vb0 = *(const f32x4*)(vsb),     vb1 = *(const f32x4*)(vsb + 4);
        f32x4 vb2 = *(const f32x4*)(vsb + 8), vb3 = *(const f32x4*)(vsb + 12);

        bf16x8 bnxt[4];
        if (nt < 1) {
#pragma unroll
            for (int ks = 0; ks < 4; ++ks)
                bnxt[ks] = *(const bf16x8*)(gB + 2048 + ks * 32);
        }

        f32x4 acc = {0.f, 0.f, 0.f, 0.f};
#pragma unroll
        for (int ks = 0; ks < 4; ++ks) {
            acc = __builtin_amdgcn_mfma_f32_16x16x32_bf16(ahi[ks], bcur[ks], acc, 0, 0, 0);
            acc = __builtin_amdgcn_mfma_f32_16x16x32_bf16(alo[ks], bcur[ks], acc, 0, 0, 0);
        }

        {   // write V reps to LDS bf16
            bf16_t* da = Vdst + ra * 72 + vpart * 16;
            bf16_t* db = Vdst + rb * 72 + vpart * 16;
            bf16x8 o0, o1;
            o0[0]=(bf16_t)va0[0]; o0[1]=(bf16_t)va0[1]; o0[2]=(bf16_t)va0[2]; o0[3]=(bf16_t)va0[3];
            o0[4]=(bf16_t)va1[0]; o0[5]=(bf16_t)va1[1]; o0[6]=(bf16_t)va1[2]; o0[7]=(bf16_t)va1[3];
            o1[0]=(bf16_t)va2[0]; o1[1]=(bf16_t)va2[1]; o1[2]=(bf16_t)va2[2]; o1[3]=(bf16_t)va2[3];
            o1[4]=(bf16_t)va3[0]; o1[5]=(bf16_t)va3[1]; o1[6]=(bf16_t)va3[2]; o1[7]=(bf16_t)va3[3];
            *(bf16x8*)(da)     = o0;
            *(bf16x8*)(da + 8) = o1;
            o0[0]=(bf16_t)vb0[0]; o0[1]=(bf16_t)vb0[1]; o0[2]=(bf16_t)vb0[2]; o0[3]=(bf16_t)vb0[3];
            o0[4]=(bf16_t)vb1[0]; o0[5]=(bf16_t)vb1[1]; o0[6]=(bf16_t)vb1[2]; o0[7]=(bf16_t)vb1[3];
            o1[0]=(bf16_t)vb2[0]; o1[1]=(bf16_t)vb2[1]; o1[2]=(bf16_t)vb2[2]; o1[3]=(bf16_t)vb2[3];
            o1[4]=(bf16_t)vb3[0]; o1[5]=(bf16_t)vb3[1]; o1[6]=(bf16_t)vb3[2]; o1[7]=(bf16_t)vb3[3];
            *(bf16x8*)(db)     = o0;
            *(bf16x8*)(db + 8) = o1;
        }

        const float cv = cvec[h * 256 + n0 + nt * 16 + fr];
        f32x4 lg = (acc + cv) * (-0.125f);
#pragma unroll
        for (int reg = 0; reg < 4; ++reg)
            Sc[(fq * 4 + reg) * 260 + n0 + nt * 16 + fr] = lg[reg];

#pragma unroll
        for (int ks = 0; ks < 4; ++ks) bcur[ks] = bnxt[ks];
    }
    __syncthreads();

    // softmax: wave w owns q rows [2w, 2w+2), lane holds katt lane*4..+3
    const int fw = w * 2;
    f32x4 sr[2];
#pragma unroll
    for (int r = 0; r < 2; ++r)
        sr[r] = *(const f32x4*)&Sc[(fw + r) * 260 + lane * 4];
#pragma unroll
    for (int r = 0; r < 2; ++r) {
        f32x4 s = sr[r];
        float mloc = fmaxf(fmaxf(s[0], s[1]), fmaxf(s[2], s[3]));
#pragma unroll
        for (int off = 32; off > 0; off >>= 1)
            mloc = fmaxf(mloc, __shfl_xor(mloc, off, 64));
        s[0] = __expf(s[0] - mloc); s[1] = __expf(s[1] - mloc);
        s[2] = __expf(s[2] - mloc); s[3] = __expf(s[3] - mloc);
        float sl = (s[0] + s[1]) + (s[2] + s[3]);
#pragma unroll
        for (int off = 32; off > 0; off >>= 1)
            sl += __shfl_xor(sl, off, 64);
        sr[r] = s * fast_rcp(sl);
    }

    // stage P hi/lo + P^2 hi/lo (rows 2w, 2w+1)
#pragma unroll
    for (int r = 0; r < 2; ++r) {
        bf16x4 phi, plo, p2hi, p2lo;
#pragma unroll
        for (int e = 0; e < 4; ++e) {
            const float p = sr[r][e];
            const bf16_t hb = (bf16_t)p;
            phi[e] = hb; plo[e] = (bf16_t)(p - (float)hb);
            const float p2 = p * p;
            const bf16_t h2 = (bf16_t)p2;
            p2hi[e] = h2; p2lo[e] = (bf16_t)(p2 - (float)h2);
        }
        const int row = fw + r;
        *(bf16x4*)&Phi[row * 264 + lane * 4] = phi;
        *(bf16x4*)&Plo[row * 264 + lane * 4] = plo;
        *(bf16x4*)&P2h[row * 264 + lane * 4] = p2hi;
        *(bf16x4*)&P2l[row * 264 + lane * 4] = p2lo;
    }
    __syncthreads();

    // PV: waves 0-3 -> mu dh tile (w&3); waves 4-7 -> var dh tile (w&3)
    const int tile = w & 3;
    const int isvar = w >> 2;
    const bf16_t* Pa = isvar ? P2h : Phi;
    const bf16_t* Pb = isvar ? P2l : Plo;
    const bf16_t* Vs = isvar ? Vsv : Vsm;
    f32x4 accp = {0.f, 0.f, 0.f, 0.f};
#pragma unroll
    for (int k0 = 0; k0 < 256; k0 += 32) {
        const int ka = k0 + fq * 8;
        bf16x8 a1 = *(const bf16x8*)&Pa[fr * 264 + ka];
        bf16x8 a2 = *(const bf16x8*)&Pb[fr * 264 + ka];
        bf16x8 bfr;
#pragma unroll
        for (int j = 0; j < 8; ++j)
            bfr[j] = Vs[(ka + j) * 72 + tile * 16 + fr];
        accp = __builtin_amdgcn_mfma_f32_16x16x32_bf16(a1, bfr, accp, 0, 0, 0);
        accp = __builtin_amdgcn_mfma_f32_16x16x32_bf16(a2, bfr, accp, 0, 0, 0);
    }

    bf16_t* Out = isvar ? Ovar : Omu;
#pragma unroll
    for (int reg = 0; reg < 4; ++reg) {
        const int qg = qt * 16 + fq * 4 + reg;
        const size_t ob = (size_t)qg * 1024 + h * 64 + tile * 16 + fr;
        Out[ob] = (bf16_t)accp[reg];
    }
}

// ---------------- launch ----------------
extern "C" void kernel_launch(void* const* d_in, const int* in_sizes, int n_in,
                              void* d_out, int out_size, void* d_ws, size_t ws_size,
                              hipStream_t stream) {
    const float* mu  = (const float*)d_in[0];
    const float* var = (const float*)d_in[1];

    uint8_t* ws = (uint8_t*)d_ws;
    bf16_t* Abf_mu  = (bf16_t*)(ws);                              // 512 KB
    bf16_t* Abf_var = (bf16_t*)(ws + (512u << 10));               // 512 KB
    bf16_t* WtB     = (bf16_t*)(ws + (1u << 20));                 // 8 x 2 MB
    float*  Proj    = (float*)(ws + (17u << 20));                 // 6 x 1 MB
    bf16_t* Obf_mu  = (bf16_t*)(ws + (23u << 20));                // 512 KB
    bf16_t* Obf_var = (bf16_t*)(ws + (23u << 20) + (512u << 10)); // 512 KB
    bf16_t* Gbf     = (bf16_t*)(ws + (24u << 20));                // 1 MB
    float*  cvec    = (float*)(ws + (25u << 20));                 // 16 KB

    PrepArgs pa;
    for (int i = 0; i < 8; ++i) pa.src[i] = (const float*)d_in[2 + 2 * i];
    pa.mu = mu; pa.var = var;
    prep_kernel<<<dim3(16, 16, 9), 256, 0, stream>>>(pa, WtB, Abf_mu, Abf_var);

    GemmArgs g1;
    for (int z = 0; z < 6; ++z) {
        g1.A[z]    = (z & 1) ? Abf_var : Abf_mu;
        g1.Wt[z]   = WtB + (size_t)z * 1048576;
        g1.bias[z] = (const float*)d_in[3 + 2 * z];
        g1.dst[z]  = Proj + (size_t)z * 262144;
        g1.splus[z] = (z & 1);
    }
    gemm_splitk<<<dim3(16, 4, 6), 256, 0, stream>>>(g1);

    feat_kernel<<<dim3(16, 4), 256, 0, stream>>>(Proj + 2 * 262144, Proj + 3 * 262144, Gbf, cvec);

    attn_v7<<<dim3(16, 16), 512, 0, stream>>>(Proj,
                                              Proj + 262144,
                                              Gbf, cvec,
                                              Proj + 4 * 262144,
                                              Proj + 5 * 262144,
                                              Obf_mu, Obf_var);

    GemmArgs g3;
    for (int z = 0; z < 6; ++z) {
        g3.A[z]    = Obf_mu;
        g3.Wt[z]   = WtB + (size_t)6 * 1048576;
        g3.bias[z] = (const float*)d_in[15];
        g3.dst[z]  = (float*)d_out;
        g3.splus[z] = 0;
    }
    g3.A[1]    = Obf_var;
    g3.Wt[1]   = WtB + (size_t)7 * 1048576;
    g3.bias[1] = (const float*)d_in[17];
    g3.dst[1]  = (float*)d_out + 262144;
    g3.splus[1] = 1;
    gemm_splitk<<<dim3(16, 4, 2), 256, 0, stream>>>(g3);
}